// Round 1
// baseline (427.860 us; speedup 1.0000x reference)
//
#include <hip/hip_runtime.h>

#define BB 16
#define SS 1024
#define HH 768
#define JJ 5
#define NEG_INF (-1e9f)

typedef __attribute__((ext_vector_type(4))) _Float16 h4_t;
typedef __attribute__((ext_vector_type(8))) _Float16 h8_t;
typedef __attribute__((ext_vector_type(4))) float f32x4;

#define WH_HALVES (JJ*HH*HH)            /* 2949120 */
#define WH_BYTES  (WH_HALVES*2)         /* 5898240 */
#define SC_FLOATS (BB*JJ*SS)            /* 81920   */
#define SC_BYTES  (SC_FLOATS*4)         /* 327680  */
#define FINAL_W   (JJ*2*HH + HH)        /* 8448    */
#define OUT2_OFF  (BB*FINAL_W)          /* 135168  */

// ---------------------------------------------------------------------------
// Kernel 0: convert W [5,768,768] f32 -> fp16, plus MFMA fragment-layout
// self-test (two candidate k-mappings for v_mfma_f32_16x16x32_f16; the
// verified C/D layout row=(lane>>4)*4+reg, col=lane&15 is used to check).
// flag = 1 (two stacked 16x16x16 halves), 2 (contiguous 8-k per lane), 0 fail.
// ---------------------------------------------------------------------------
__global__ void k_convert_w(const float* __restrict__ W, _Float16* __restrict__ Wh,
                            int* __restrict__ flag)
{
    int i = blockIdx.x * 256 + threadIdx.x;
    if (i < WH_HALVES / 4) {
        float4 v = *(const float4*)(W + (size_t)i * 4);
        h4_t hv = { (_Float16)v.x, (_Float16)v.y, (_Float16)v.z, (_Float16)v.w };
        *(h4_t*)(Wh + (size_t)i * 4) = hv;
    }
    if (blockIdx.x == 0 && threadIdx.x < 64) {
        int l = threadIdx.x, l15 = l & 15, lg = l >> 4;
        h8_t a1, b1, a2, b2;
#pragma unroll
        for (int jj = 0; jj < 8; ++jj) {
            int k1 = (jj & 3) + 4 * lg + 16 * (jj >> 2);   // layout 1
            int k2 = jj + 8 * lg;                          // layout 2
            a1[jj] = (_Float16)(float)((l15 * 31 + k1 * 17) % 13 - 6);
            b1[jj] = (_Float16)(float)((k1 * 7 + l15 * 5) % 11 - 5);
            a2[jj] = (_Float16)(float)((l15 * 31 + k2 * 17) % 13 - 6);
            b2[jj] = (_Float16)(float)((k2 * 7 + l15 * 5) % 11 - 5);
        }
        f32x4 z = { 0.f, 0.f, 0.f, 0.f };
        f32x4 c1 = __builtin_amdgcn_mfma_f32_16x16x32_f16(a1, b1, z, 0, 0, 0);
        f32x4 c2 = __builtin_amdgcn_mfma_f32_16x16x32_f16(a2, b2, z, 0, 0, 0);
        int ok1 = 1, ok2 = 1;
#pragma unroll
        for (int r = 0; r < 4; ++r) {
            int row = lg * 4 + r;
            float ref = 0.f;
            for (int k = 0; k < 32; ++k)
                ref += (float)((row * 31 + k * 17) % 13 - 6) *
                       (float)((k * 7 + l15 * 5) % 11 - 5);
            ok1 &= (c1[r] == ref);
            ok2 &= (c2[r] == ref);
        }
        int all1 = __all(ok1);
        int all2 = __all(ok2);
        if (l == 0) flag[0] = all1 ? 1 : (all2 ? 2 : 0);
    }
}

// ---------------------------------------------------------------------------
// Kernel A: scores[b,j,s] = q_j . tanh(W_j h_s + b_j) for s in span, else -1e9
// Block = (64-row tile, j, b); 4 waves; wave covers 64 rows x 64 cols per
// pass, 3 passes over n (768). A staged in LDS fragment-linear fp16,
// B fragments loaded straight from global fp16 W.
// ---------------------------------------------------------------------------
template<int LAYOUT>
__device__ __forceinline__ void scores_body(
    const float* __restrict__ hsrc,      // hidden + (b*SS+s0)*HH
    const _Float16* __restrict__ wbase,  // Wh + j*HH*HH
    const float* __restrict__ qv,        // attn_q + j*HH
    const float* __restrict__ bv,        // attn_b + j*HH
    _Float16* Alds, float* s_accw, int tid)
{
    // ---- stage A tile (64 x 768) f32 -> fp16 fragment-linear layout ----
    for (int i = 0; i < 48; ++i) {
        int f4 = i * 256 + tid;          // 0..12287
        int m  = f4 / 192;               // row 0..63
        int c4 = f4 - m * 192;
        int k  = c4 * 4;
        float4 v = *(const float4*)(hsrc + m * HH + k);
        int mf = m >> 4, mr = m & 15;
        int ks = k >> 5, kk = k & 31;    // kk in {0,4,...,28}
        int g, j0;
        if (LAYOUT == 2) { g = kk >> 3;        j0 = kk & 7; }
        else             { g = (kk & 15) >> 2; j0 = (kk >> 4) << 2; }
        int chunk = ((mf * 24 + ks) * 4 + g) * 17 + mr;  // 16B chunks, +1 pad per g
        h4_t hv = { (_Float16)v.x, (_Float16)v.y, (_Float16)v.z, (_Float16)v.w };
        *(h4_t*)(Alds + chunk * 8 + j0) = hv;
    }
    __syncthreads();

    const int wave = tid >> 6, lane = tid & 63;
    const int l15 = lane & 15, lg = lane >> 4;

    for (int p = 0; p < 3; ++p) {
        const int nbase = p * 256 + wave * 64;
        f32x4 acc[4][4];
#pragma unroll
        for (int a = 0; a < 4; ++a)
#pragma unroll
            for (int c = 0; c < 4; ++c) acc[a][c] = (f32x4){0.f, 0.f, 0.f, 0.f};

        for (int ks = 0; ks < 24; ++ks) {
            h8_t bfr[4];
#pragma unroll
            for (int nf = 0; nf < 4; ++nf) {
                const _Float16* wp = wbase + (nbase + nf * 16 + l15) * HH + ks * 32;
                if (LAYOUT == 2) {
                    bfr[nf] = *(const h8_t*)(wp + lg * 8);
                } else {
                    h4_t lo = *(const h4_t*)(wp + lg * 4);
                    h4_t hi = *(const h4_t*)(wp + 16 + lg * 4);
                    h8_t t;
                    t[0] = lo[0]; t[1] = lo[1]; t[2] = lo[2]; t[3] = lo[3];
                    t[4] = hi[0]; t[5] = hi[1]; t[6] = hi[2]; t[7] = hi[3];
                    bfr[nf] = t;
                }
            }
            h8_t afr[4];
#pragma unroll
            for (int mf = 0; mf < 4; ++mf) {
                int chunk = ((mf * 24 + ks) * 4 + lg) * 17 + l15;
                afr[mf] = *(const h8_t*)(Alds + chunk * 8);
            }
#pragma unroll
            for (int mf = 0; mf < 4; ++mf)
#pragma unroll
                for (int nf = 0; nf < 4; ++nf)
                    acc[mf][nf] = __builtin_amdgcn_mfma_f32_16x16x32_f16(
                        afr[mf], bfr[nf], acc[mf][nf], 0, 0, 0);
        }

        // ---- epilogue: +bias, tanh, * q, reduce over this wave's 64 cols ----
        float qn[4], bn[4];
#pragma unroll
        for (int nf = 0; nf < 4; ++nf) {
            int n = nbase + nf * 16 + l15;
            qn[nf] = qv[n];
            bn[nf] = bv[n];
        }
#pragma unroll
        for (int mf = 0; mf < 4; ++mf) {
#pragma unroll
            for (int r = 0; r < 4; ++r) {
                float ssum = 0.f;
#pragma unroll
                for (int nf = 0; nf < 4; ++nf) {
                    float y = acc[mf][nf][r] + bn[nf];
                    y = fminf(fmaxf(y, -15.f), 15.f);
                    float e = __expf(2.f * y);
                    ssum += qn[nf] * ((e - 1.f) / (e + 1.f));
                }
#pragma unroll
                for (int off = 1; off < 16; off <<= 1)
                    ssum += __shfl_xor(ssum, off, 64);
                if (l15 == 0) s_accw[wave * 64 + mf * 16 + lg * 4 + r] += ssum;
            }
        }
    }
}

__global__ __launch_bounds__(256) void k_scores(
    const float* __restrict__ hidden, const _Float16* __restrict__ Wh,
    const float* __restrict__ attn_b, const float* __restrict__ attn_q,
    const int* __restrict__ spans, float* __restrict__ scores,
    const int* __restrict__ flag)
{
    const int tile = blockIdx.x, j = blockIdx.y, b = blockIdx.z;
    const int s0 = tile * 64;
    const int start = spans[(b * JJ + j) * 2 + 0];
    const int end   = spans[(b * JJ + j) * 2 + 1];
    float* sc = scores + (b * JJ + j) * SS + s0;
    const int tid = threadIdx.x;

    if (s0 >= end || s0 + 64 <= start) {
        if (tid < 64) sc[tid] = NEG_INF;
        return;
    }

    __shared__ __align__(16) _Float16 Alds[4 * 24 * 4 * 17 * 8]; // 104448 B
    __shared__ float s_accw[4 * 64];
    s_accw[tid] = 0.f;

    const float* hsrc = hidden + ((size_t)(b * SS + s0)) * HH;
    const _Float16* wbase = Wh + j * HH * HH;
    const float* qv = attn_q + j * HH;
    const float* bvp = attn_b + j * HH;

    int layout = flag[0];
    if (layout == 2) scores_body<2>(hsrc, wbase, qv, bvp, Alds, s_accw, tid);
    else             scores_body<1>(hsrc, wbase, qv, bvp, Alds, s_accw, tid);

    __syncthreads();
    if (tid < 64) {
        float v = s_accw[tid] + s_accw[64 + tid] + s_accw[128 + tid] + s_accw[192 + tid];
        int s = s0 + tid;
        sc[tid] = (s >= start && s < end) ? v : NEG_INF;
    }
}

// ---------------------------------------------------------------------------
// Kernel B: per (h-chunk, j, b): softmax over span + mean/att pooling,
// writes straight into final[b, j*1536 + {0,768} + h].
// ---------------------------------------------------------------------------
__global__ __launch_bounds__(256) void k_pool(
    const float* __restrict__ hidden, const float* __restrict__ scores,
    const int* __restrict__ spans, float* __restrict__ out)
{
    const int hc = blockIdx.x, j = blockIdx.y, b = blockIdx.z;
    const int tid = threadIdx.x;
    const int h = hc * 256 + tid;
    const int start = spans[(b * JJ + j) * 2 + 0];
    const int end   = spans[(b * JJ + j) * 2 + 1];
    const int count = end - start;
    float* fin = out + (size_t)b * FINAL_W + j * (2 * HH);

    if (count <= 0) {
        fin[h] = 0.f;
        fin[HH + h] = 0.f;
        return;
    }

    const float* sc = scores + (b * JJ + j) * SS;
    __shared__ float red[8];
    __shared__ float wbuf[SS];

    // max
    float lm = -3.0e38f;
    for (int s = start + tid; s < end; s += 256) lm = fmaxf(lm, sc[s]);
#pragma unroll
    for (int off = 32; off > 0; off >>= 1) lm = fmaxf(lm, __shfl_xor(lm, off, 64));
    int wid = tid >> 6, lane = tid & 63;
    if (lane == 0) red[wid] = lm;
    __syncthreads();
    float m = fmaxf(fmaxf(red[0], red[1]), fmaxf(red[2], red[3]));

    // denom
    float ld = 0.f;
    for (int s = start + tid; s < end; s += 256) ld += __expf(sc[s] - m);
#pragma unroll
    for (int off = 32; off > 0; off >>= 1) ld += __shfl_xor(ld, off, 64);
    if (lane == 0) red[4 + wid] = ld;
    __syncthreads();
    float inv_d = 1.f / (red[4] + red[5] + red[6] + red[7]);

    // weights to LDS
    for (int s = start + tid; s < end; s += 256)
        wbuf[s - start] = __expf(sc[s] - m) * inv_d;
    __syncthreads();

    float am = 0.f, aa = 0.f;
    const float* hp = hidden + ((size_t)b * SS) * HH + h;
    for (int i = 0; i < count; ++i) {
        float x = hp[(size_t)(start + i) * HH];
        am += x;
        aa += wbuf[i] * x;
    }
    fin[h] = am / (float)count;
    fin[HH + h] = aa;
}

// ---------------------------------------------------------------------------
// Tail: full_emb -> final[b, 7680:8448] and second output.
// ---------------------------------------------------------------------------
__global__ void k_tail(const float* __restrict__ full_emb, float* __restrict__ out)
{
    int i = blockIdx.x * 256 + threadIdx.x;   // 0..12287
    if (i >= BB * HH) return;
    int b = i / HH, h = i - b * HH;
    float v = full_emb[i];
    out[(size_t)b * FINAL_W + JJ * 2 * HH + h] = v;
    out[OUT2_OFF + i] = v;
}

// ---------------------------------------------------------------------------
extern "C" void kernel_launch(void* const* d_in, const int* in_sizes, int n_in,
                              void* d_out, int out_size, void* d_ws, size_t ws_size,
                              hipStream_t stream)
{
    const float* hidden   = (const float*)d_in[0];
    const float* full_emb = (const float*)d_in[1];
    const float* attn_W   = (const float*)d_in[2];
    const float* attn_b   = (const float*)d_in[3];
    const float* attn_q   = (const float*)d_in[4];
    const int*   spans    = (const int*)d_in[5];
    float* out = (float*)d_out;

    _Float16* Wh  = (_Float16*)d_ws;
    float* scores = (float*)((char*)d_ws + WH_BYTES);
    int*   flag   = (int*)((char*)d_ws + WH_BYTES + SC_BYTES);

    k_convert_w<<<(WH_HALVES / 4 + 255) / 256, 256, 0, stream>>>(attn_W, Wh, flag);
    k_scores<<<dim3(SS / 64, JJ, BB), 256, 0, stream>>>(hidden, Wh, attn_b, attn_q,
                                                        spans, scores, flag);
    k_pool<<<dim3(HH / 256, JJ, BB), 256, 0, stream>>>(hidden, scores, spans, out);
    k_tail<<<(BB * HH + 255) / 256, 256, 0, stream>>>(full_emb, out);
}